// Round 4
// baseline (310.938 us; speedup 1.0000x reference)
//
#include <hip/hip_runtime.h>
#include <hip/hip_bf16.h>

// GATv2 x2 + LayerNorm, B=2 N=512 DIN=32 DH=DOUT=64 H=4.
// All inputs/outputs fp32 (reference dtype); internal math fp32.

#define BB   2
#define NN   512
#define DIN  32
#define DH   64
#define HH   4
#define C1   256   // H*DH
#define C2   256   // H*DOUT
#define NEG  0.2f
#define LEPS 1e-5f

__device__ __forceinline__ float wave_sum(float v) {
#pragma unroll
    for (int o = 32; o > 0; o >>= 1) v += __shfl_down(v, o, 64);
    return v;
}
__device__ __forceinline__ float wave_max(float v) {
#pragma unroll
    for (int o = 32; o > 0; o >>= 1) v = fmaxf(v, __shfl_down(v, o, 64));
    return v;
}

// --- normalize embedding rows: ne[r,:] = e[r,:] * rsqrt(sum e^2) ---
__global__ void ne_k(const float* __restrict__ emb, float* __restrict__ ne) {
    int r = blockIdx.x, t = threadIdx.x;           // 64 threads
    float v = emb[r * DH + t];
    float ss = wave_sum(v * v);
    ss = __shfl(ss, 0, 64);
    ne[r * DH + t] = v * rsqrtf(ss);
}

// --- mask[i,j] = (ne_i . ne_j != 0) || (i==j) ---
__global__ void mask_k(const float* __restrict__ ne, unsigned char* __restrict__ mask) {
    __shared__ float s_ni[DH];
    int i = blockIdx.x, t = threadIdx.x;           // 256 threads
    if (t < DH) s_ni[t] = ne[i * DH + t];
    __syncthreads();
#pragma unroll
    for (int rep = 0; rep < 2; rep++) {
        int j = t + rep * 256;
        const float* nj = ne + j * DH;
        float acc = 0.f;
#pragma unroll
        for (int d = 0; d < DH; d++) acc += s_ni[d] * nj[d];
        mask[i * NN + j] = (acc != 0.f || i == j) ? 1 : 0;
    }
}

// --- layer1 projections: xl = x@wl + bl, xr = x@wr + br  (K=32) ---
__global__ void proj1_k(const float* __restrict__ x,
                        const float* __restrict__ wl, const float* __restrict__ bl,
                        const float* __restrict__ wr, const float* __restrict__ br,
                        float* __restrict__ xl, float* __restrict__ xr) {
    __shared__ float s_x[DIN];
    int row = blockIdx.x, t = threadIdx.x;         // 256 threads
    if (t < DIN) s_x[t] = x[row * DIN + t];
    __syncthreads();
    float al = bl[t], ar = br[t];
#pragma unroll
    for (int k = 0; k < DIN; k++) {
        float xv = s_x[k];
        al += xv * wl[k * C1 + t];
        ar += xv * wr[k * C1 + t];
    }
    xl[row * C1 + t] = al;
    xr[row * C1 + t] = ar;
}

// --- layer2 projections (K=256) ---
__global__ void proj2_k(const float* __restrict__ hin,
                        const float* __restrict__ wl, const float* __restrict__ bl,
                        const float* __restrict__ wr, const float* __restrict__ br,
                        float* __restrict__ xl, float* __restrict__ xr) {
    __shared__ float s_h[C1];
    int row = blockIdx.x, t = threadIdx.x;         // 256 threads
    s_h[t] = hin[row * C1 + t];
    __syncthreads();
    float al = bl[t], ar = br[t];
#pragma unroll 8
    for (int k = 0; k < C1; k++) {
        float xv = s_h[k];
        al += xv * wl[k * C2 + t];
        ar += xv * wr[k * C2 + t];
    }
    xl[row * C2 + t] = al;
    xr[row * C2 + t] = ar;
}

// --- GATv2 attention: one block per (i, h, b) ---
// e_j = att_h . leaky_relu(xl_j + xr_i); softmax over j (masked);
// out[b,i,h*64+d] = sum_j alpha_j xl[b,j,h*64+d] + bias[h*64+d]
__global__ void attn_k(const float* __restrict__ xl, const float* __restrict__ xr,
                       const float* __restrict__ att, const float* __restrict__ bias,
                       const unsigned char* __restrict__ mask, float* __restrict__ out) {
    __shared__ float s_xr[DH], s_att[DH], s_p[NN], s_part[256], s_red[8];
    int i = blockIdx.x, h = blockIdx.y, b = blockIdx.z;
    int t = threadIdx.x;                           // 256 threads
    int lane = t & 63, wid = t >> 6;

    if (t < DH) {
        s_xr[t]  = xr[((b * NN + i) * C1) + h * DH + t];
        s_att[t] = att[h * DH + t];
    }
    __syncthreads();

    // scores
#pragma unroll
    for (int rep = 0; rep < 2; rep++) {
        int j = t + rep * 256;
        float e;
        if (mask[i * NN + j]) {
            const float* xlr = xl + ((b * NN + j) * C1 + h * DH);
            float acc = 0.f;
#pragma unroll
            for (int d = 0; d < DH; d++) {
                float z = xlr[d] + s_xr[d];
                z = (z > 0.f) ? z : NEG * z;
                acc += s_att[d] * z;
            }
            e = acc;
        } else {
            e = -INFINITY;
        }
        s_p[j] = e;
    }
    __syncthreads();

    // softmax (max, exp, sum)
    float m = fmaxf(s_p[t], s_p[t + 256]);
    m = wave_max(m);
    if (lane == 0) s_red[wid] = m;
    __syncthreads();
    m = fmaxf(fmaxf(s_red[0], s_red[1]), fmaxf(s_red[2], s_red[3]));
    float p0 = expf(s_p[t] - m);
    float p1 = expf(s_p[t + 256] - m);
    s_p[t] = p0;
    s_p[t + 256] = p1;
    float sm = wave_sum(p0 + p1);
    if (lane == 0) s_red[4 + wid] = sm;
    __syncthreads();
    float invS = 1.f / (s_red[4] + s_red[5] + s_red[6] + s_red[7]);

    // aggregate: thread t handles d = t&63, j-chunk = t>>6
    int d = t & 63, chunk = t >> 6;
    const float* xb = xl + (size_t)b * NN * C1 + h * DH + d;
    float acc = 0.f;
    int j0 = chunk * 128;
#pragma unroll 4
    for (int j = j0; j < j0 + 128; j++) acc += s_p[j] * xb[(size_t)j * C1];
    s_part[t] = acc;
    __syncthreads();
    if (t < DH) {
        float o = (s_part[t] + s_part[t + 64] + s_part[t + 128] + s_part[t + 192]) * invS
                  + bias[h * DH + t];
        out[((b * NN + i) * C1) + h * DH + t] = o;
    }
}

// --- LayerNorm over last dim (256), optional ReLU ---
// In-place safe (each element read once by its own thread before its write).
// NOTE: no __restrict__ on in/out — they may alias.
template <bool RELU>
__global__ void ln_k(const float* in, const float* __restrict__ g,
                     const float* __restrict__ be, float* out) {
    __shared__ float scr[4];
    int row = blockIdx.x, t = threadIdx.x;         // 256 threads
    int lane = t & 63, wid = t >> 6;
    float v = in[row * 256 + t];
    float s = wave_sum(v);
    if (lane == 0) scr[wid] = s;
    __syncthreads();
    float mu = (scr[0] + scr[1] + scr[2] + scr[3]) * (1.f / 256.f);
    float dv = v - mu;
    float s2 = wave_sum(dv * dv);
    __syncthreads();
    if (lane == 0) scr[wid] = s2;
    __syncthreads();
    float var = (scr[0] + scr[1] + scr[2] + scr[3]) * (1.f / 256.f);
    float y = dv * rsqrtf(var + LEPS) * g[t] + be[t];
    if (RELU) y = fmaxf(y, 0.f);
    out[row * 256 + t] = y;
}

extern "C" void kernel_launch(void* const* d_in, const int* in_sizes, int n_in,
                              void* d_out, int out_size, void* d_ws, size_t ws_size,
                              hipStream_t stream) {
    const float* x    = (const float*)d_in[0];
    const float* emb  = (const float*)d_in[1];
    const float* w1l  = (const float*)d_in[2];
    const float* b1l  = (const float*)d_in[3];
    const float* w1r  = (const float*)d_in[4];
    const float* b1r  = (const float*)d_in[5];
    const float* att1 = (const float*)d_in[6];
    const float* bia1 = (const float*)d_in[7];
    const float* g1   = (const float*)d_in[8];
    const float* be1  = (const float*)d_in[9];
    const float* w2l  = (const float*)d_in[10];
    const float* b2l  = (const float*)d_in[11];
    const float* w2r  = (const float*)d_in[12];
    const float* b2r  = (const float*)d_in[13];
    const float* att2 = (const float*)d_in[14];
    const float* bia2 = (const float*)d_in[15];
    const float* g2   = (const float*)d_in[16];
    const float* be2  = (const float*)d_in[17];

    // Workspace layout (reused): total ~3.4 MB
    char* w = (char*)d_ws;
    float* ne            = (float*)w;          w += NN * DH * 4;        // 128 KB
    unsigned char* mask  = (unsigned char*)w;  w += NN * NN;            // 256 KB
    float* xl            = (float*)w;          w += BB * NN * C1 * 4;   // 1 MB (layer1 & layer2)
    float* xr            = (float*)w;          w += BB * NN * C1 * 4;   // 1 MB (layer1 & layer2)
    float* ho            = (float*)w;          w += BB * NN * C1 * 4;   // 1 MB (attn out / h)

    ne_k<<<NN, 64, 0, stream>>>(emb, ne);
    mask_k<<<NN, 256, 0, stream>>>(ne, mask);
    proj1_k<<<BB * NN, 256, 0, stream>>>(x, w1l, b1l, w1r, b1r, xl, xr);
    attn_k<<<dim3(NN, HH, BB), 256, 0, stream>>>(xl, xr, att1, bia1, mask, ho);
    ln_k<true><<<BB * NN, 256, 0, stream>>>(ho, g1, be1, ho);   // in-place LN+ReLU
    proj2_k<<<BB * NN, 256, 0, stream>>>(ho, w2l, b2l, w2r, b2r, xl, xr);
    attn_k<<<dim3(NN, HH, BB), 256, 0, stream>>>(xl, xr, att2, bia2, mask, ho);
    ln_k<false><<<BB * NN, 256, 0, stream>>>(ho, g2, be2, (float*)d_out);
}

// Round 6
// 281.895 us; speedup vs baseline: 1.1030x; 1.1030x over previous
//
#include <hip/hip_runtime.h>
#include <hip/hip_bf16.h>

// GATv2 x2 + LayerNorm, B=2 N=512 DIN=32 DH=DOUT=64 H=4. fp32 in/out.
// R5: i-tiled LDS attention (TI=16, grid=256=1 block/CU), wave-private
// softmax rows, fused LN1+proj2, standalone raw-dot mask kernel.

#define BB   2
#define NN   512
#define DIN  32
#define DH   64
#define HH   4
#define C1   256
#define C2   256
#define TI   16
#define LEPS 1e-5f

__device__ __forceinline__ float bf_sum(float v) {
#pragma unroll
    for (int o = 32; o > 0; o >>= 1) v += __shfl_xor(v, o, 64);
    return v;
}
__device__ __forceinline__ float bf_max(float v) {
#pragma unroll
    for (int o = 32; o > 0; o >>= 1) v = fmaxf(v, __shfl_xor(v, o, 64));
    return v;
}

// --- mask[i,j] = (dot(emb_i, emb_j) != 0) || (i==j) ---
// grid (32 i-tiles, 4 j-quarters), 256 thr. Raw dot has the same zero-set
// as the normalized cosine dot (post-scale by positive norms can't flip !=0).
__global__ __launch_bounds__(256) void mask_k(const float* __restrict__ emb,
                                              unsigned char* __restrict__ mask) {
    __shared__ __align__(16) float s_ei[TI][DH];
    __shared__ float ebuf[64][DH + 1];
    int it = blockIdx.x, jq = blockIdx.y;
    int t = threadIdx.x, lane = t & 63, iq = t >> 6;
    {   // stage 16 emb i-rows (1024 floats, float4-coalesced)
        int row = t >> 4, d4 = (t & 15) << 2;
        *(float4*)&s_ei[row][d4] = *(const float4*)(emb + (it * TI + row) * DH + d4);
    }
    for (int jt = 0; jt < 2; jt++) {
        int j0 = jq * 128 + jt * 64;
        __syncthreads();
#pragma unroll
        for (int k = 0; k < 4; k++) {        // stage 64 emb j-rows
            int idx = k * 256 + t, jl = idx >> 4, d4 = (idx & 15) << 2;
            float4 v = *(const float4*)(emb + (j0 + jl) * DH + d4);
            ebuf[jl][d4] = v.x; ebuf[jl][d4 + 1] = v.y;
            ebuf[jl][d4 + 2] = v.z; ebuf[jl][d4 + 3] = v.w;
        }
        __syncthreads();
        float acc[4] = {0.f, 0.f, 0.f, 0.f};
        for (int dc = 0; dc < 16; dc++) {
            int d = dc * 4;
            float e0 = ebuf[lane][d], e1 = ebuf[lane][d + 1];
            float e2 = ebuf[lane][d + 2], e3 = ebuf[lane][d + 3];
#pragma unroll
            for (int r = 0; r < 4; r++) {
                float4 iv = *(const float4*)&s_ei[iq * 4 + r][d];
                acc[r] += iv.x * e0 + iv.y * e1 + iv.z * e2 + iv.w * e3;
            }
        }
        int jg = j0 + lane;
#pragma unroll
        for (int r = 0; r < 4; r++) {
            int ig = it * TI + iq * 4 + r;
            mask[ig * NN + jg] = (acc[r] != 0.f || ig == jg) ? 1 : 0;
        }
    }
}

// --- proj1: 4 rows/block, K=32 ---
__global__ __launch_bounds__(256) void proj1_k(const float* __restrict__ x,
        const float* __restrict__ wl, const float* __restrict__ bl,
        const float* __restrict__ wr, const float* __restrict__ br,
        float* __restrict__ xl, float* __restrict__ xr) {
    __shared__ float s_x[4][DIN];
    int t = threadIdx.x, row0 = blockIdx.x * 4;
    if (t < 128) s_x[t >> 5][t & 31] = x[(row0 + (t >> 5)) * DIN + (t & 31)];
    __syncthreads();
    float al[4], ar[4];
    float blv = bl[t], brv = br[t];
#pragma unroll
    for (int r = 0; r < 4; r++) { al[r] = blv; ar[r] = brv; }
#pragma unroll
    for (int k = 0; k < DIN; k++) {
        float wlv = wl[k * C1 + t], wrv = wr[k * C1 + t];
#pragma unroll
        for (int r = 0; r < 4; r++) {
            float hv = s_x[r][k];
            al[r] += hv * wlv; ar[r] += hv * wrv;
        }
    }
#pragma unroll
    for (int r = 0; r < 4; r++) {
        xl[(size_t)(row0 + r) * C1 + t] = al[r];
        xr[(size_t)(row0 + r) * C1 + t] = ar[r];
    }
}

// --- fused LN(g1,be1)+ReLU + proj2 (K=256), 4 rows/block ---
__global__ __launch_bounds__(256) void projln_k(const float* __restrict__ ho,
        const float* __restrict__ g, const float* __restrict__ be,
        const float* __restrict__ wl, const float* __restrict__ bl,
        const float* __restrict__ wr, const float* __restrict__ br,
        float* __restrict__ xl, float* __restrict__ xr) {
    __shared__ __align__(16) float s_h[4][C1];
    int t = threadIdx.x, lane = t & 63, w = t >> 6;
    int row0 = blockIdx.x * 4;
    {   // wave w normalizes row row0+w
        const float* src = ho + (size_t)(row0 + w) * C1;
        float4 v = *(const float4*)(src + (lane << 2));
        float mu = bf_sum(v.x + v.y + v.z + v.w) * (1.f / 256.f);
        float dx = v.x - mu, dy = v.y - mu, dz = v.z - mu, dw = v.w - mu;
        float var = bf_sum(dx * dx + dy * dy + dz * dz + dw * dw) * (1.f / 256.f);
        float rs = rsqrtf(var + LEPS);
        float4 gv = *(const float4*)(g + (lane << 2));
        float4 bv = *(const float4*)(be + (lane << 2));
        float4 y;
        y.x = fmaxf(dx * rs * gv.x + bv.x, 0.f);
        y.y = fmaxf(dy * rs * gv.y + bv.y, 0.f);
        y.z = fmaxf(dz * rs * gv.z + bv.z, 0.f);
        y.w = fmaxf(dw * rs * gv.w + bv.w, 0.f);
        *(float4*)&s_h[w][lane << 2] = y;
    }
    __syncthreads();
    float al[4], ar[4];
    float blv = bl[t], brv = br[t];
#pragma unroll
    for (int r = 0; r < 4; r++) { al[r] = blv; ar[r] = brv; }
#pragma unroll 8
    for (int k = 0; k < C1; k++) {
        float wlv = wl[k * C2 + t], wrv = wr[k * C2 + t];
#pragma unroll
        for (int r = 0; r < 4; r++) {
            float hv = s_h[r][k];
            al[r] += hv * wlv; ar[r] += hv * wrv;
        }
    }
#pragma unroll
    for (int r = 0; r < 4; r++) {
        xl[(size_t)(row0 + r) * C2 + t] = al[r];
        xr[(size_t)(row0 + r) * C2 + t] = ar[r];
    }
}

// --- GATv2 attention, i-tiled. Block = (i-tile of 16, h, b), 256 thr. ---
// Wave iq owns rows iq*4..iq*4+3 of s_e through scores/softmax/aggregate
// (no barriers needed around softmax). xl staged tile-by-tile with reg prefetch.
__global__ __launch_bounds__(256) void attn_k(const float* __restrict__ xl,
        const float* __restrict__ xr, const float* __restrict__ att,
        const float* __restrict__ bias, const unsigned char* __restrict__ mask,
        float* __restrict__ out) {
    __shared__ __align__(16) float s_xr[TI][DH];
    __shared__ __align__(16) float s_att[DH];
    __shared__ float xbuf[64][DH + 1];           // +1 pad: conflict-free both phases
    __shared__ __align__(16) float s_e[TI][NN];
    __shared__ float s_inv[TI];
    __shared__ unsigned char s_mask[TI][NN];

    int it = blockIdx.x, h = blockIdx.y, b = blockIdx.z;
    int t = threadIdx.x, lane = t & 63, iq = t >> 6;
    int i0 = it * TI;

    {   // stage xr i-tile (float4 coalesced)
        int row = t >> 4, d4 = (t & 15) << 2;
        *(float4*)&s_xr[row][d4] =
            *(const float4*)(xr + (size_t)(b * NN + i0 + row) * C1 + h * DH + d4);
    }
    if (t < DH) s_att[t] = att[h * DH + t];
    {   // stage mask rows (8 KB as u32)
        const unsigned int* msrc = (const unsigned int*)(mask + (size_t)i0 * NN);
        unsigned int* mdst = (unsigned int*)&s_mask[0][0];
#pragma unroll
        for (int k = 0; k < 8; k++) mdst[k * 256 + t] = msrc[k * 256 + t];
    }

    float4 xa[4];
    int pidx[4][2];
#pragma unroll
    for (int k = 0; k < 4; k++) {
        int idx = k * 256 + t;
        pidx[k][0] = idx >> 4;            // j-local
        pidx[k][1] = (idx & 15) << 2;     // d4
    }
    const float* xlbase = xl + (size_t)b * NN * C1 + h * DH;

    // ---------------- pass 1: scores ----------------
#pragma unroll
    for (int k = 0; k < 4; k++)
        xa[k] = *(const float4*)(xlbase + (size_t)(0 * 64 + pidx[k][0]) * C1 + pidx[k][1]);
    for (int jt = 0; jt < 8; jt++) {
        __syncthreads();
#pragma unroll
        for (int k = 0; k < 4; k++) {
            int jl = pidx[k][0], d4 = pidx[k][1];
            xbuf[jl][d4] = xa[k].x; xbuf[jl][d4 + 1] = xa[k].y;
            xbuf[jl][d4 + 2] = xa[k].z; xbuf[jl][d4 + 3] = xa[k].w;
        }
        __syncthreads();
        if (jt < 7) {
#pragma unroll
            for (int k = 0; k < 4; k++)
                xa[k] = *(const float4*)(xlbase + (size_t)((jt + 1) * 64 + pidx[k][0]) * C1 + pidx[k][1]);
        }
        float acc1[4] = {0.f, 0.f, 0.f, 0.f}, acc2[4] = {0.f, 0.f, 0.f, 0.f};
        for (int dc = 0; dc < 16; dc++) {
            int d = dc * 4;
            float x0 = xbuf[lane][d], x1 = xbuf[lane][d + 1];
            float x2 = xbuf[lane][d + 2], x3 = xbuf[lane][d + 3];
            float4 av = *(const float4*)&s_att[d];
#pragma unroll
            for (int r = 0; r < 4; r++) {
                float4 rv = *(const float4*)&s_xr[iq * 4 + r][d];
                float z0 = x0 + rv.x, z1 = x1 + rv.y, z2 = x2 + rv.z, z3 = x3 + rv.w;
                acc1[r] += av.x * z0 + av.y * z1 + av.z * z2 + av.w * z3;
                acc2[r] += av.x * fabsf(z0) + av.y * fabsf(z1)
                         + av.z * fabsf(z2) + av.w * fabsf(z3);
            }
        }
        int jg = jt * 64 + lane;
#pragma unroll
        for (int r = 0; r < 4; r++) {
            int il = iq * 4 + r;
            // leaky_relu(z) = 0.6z + 0.4|z| for slope 0.2
            float e = 0.6f * acc1[r] + 0.4f * acc2[r];
            s_e[il][jg] = s_mask[il][jg] ? e : -INFINITY;
        }
    }

    // ---------------- softmax (wave-private rows, no barrier) ----------------
#pragma unroll
    for (int r = 0; r < 4; r++) {
        int il = iq * 4 + r;
        float v[8], m = -INFINITY;
#pragma unroll
        for (int k = 0; k < 8; k++) { v[k] = s_e[il][lane + 64 * k]; m = fmaxf(m, v[k]); }
        m = bf_max(m);
        float s = 0.f;
#pragma unroll
        for (int k = 0; k < 8; k++) { v[k] = expf(v[k] - m); s += v[k]; }
        s = bf_sum(s);
#pragma unroll
        for (int k = 0; k < 8; k++) s_e[il][lane + 64 * k] = v[k];
        if (lane == 0) s_inv[il] = 1.f / s;
    }

    // ---------------- pass 2: aggregate ----------------
    float agg[4] = {0.f, 0.f, 0.f, 0.f};
#pragma unroll
    for (int k = 0; k < 4; k++)
        xa[k] = *(const float4*)(xlbase + (size_t)(0 * 64 + pidx[k][0]) * C1 + pidx[k][1]);
    for (int jt = 0; jt < 8; jt++) {
        __syncthreads();
#pragma unroll
        for (int k = 0; k < 4; k++) {
            int jl = pidx[k][0], d4 = pidx[k][1];
            xbuf[jl][d4] = xa[k].x; xbuf[jl][d4 + 1] = xa[k].y;
            xbuf[jl][d4 + 2] = xa[k].z; xbuf[jl][d4 + 3] = xa[k].w;
        }
        __syncthreads();
        if (jt < 7) {
#pragma unroll
            for (int k = 0; k < 4; k++)
                xa[k] = *(const float4*)(xlbase + (size_t)((jt + 1) * 64 + pidx[k][0]) * C1 + pidx[k][1]);
        }
        for (int jc = 0; jc < 16; jc++) {
            int j = jc * 4;
            float x0 = xbuf[j][lane], x1 = xbuf[j + 1][lane];
            float x2 = xbuf[j + 2][lane], x3 = xbuf[j + 3][lane];
#pragma unroll
            for (int r = 0; r < 4; r++) {
                float4 p = *(const float4*)&s_e[iq * 4 + r][jt * 64 + j];
                agg[r] += p.x * x0 + p.y * x1 + p.z * x2 + p.w * x3;
            }
        }
    }
    float bv = bias[h * DH + lane];
#pragma unroll
    for (int r = 0; r < 4; r++) {
        int il = iq * 4 + r;
        out[(size_t)(b * NN + i0 + il) * C1 + h * DH + lane] = agg[r] * s_inv[il] + bv;
    }
}

// --- final LayerNorm, wave-per-row, grid 256 ---
__global__ __launch_bounds__(256) void ln2_k(const float* __restrict__ in,
        const float* __restrict__ g, const float* __restrict__ be,
        float* __restrict__ outp) {
    int t = threadIdx.x, lane = t & 63, w = t >> 6;
    size_t row = blockIdx.x * 4 + w;
    float4 v = *(const float4*)(in + row * C1 + (lane << 2));
    float mu = bf_sum(v.x + v.y + v.z + v.w) * (1.f / 256.f);
    float dx = v.x - mu, dy = v.y - mu, dz = v.z - mu, dw = v.w - mu;
    float var = bf_sum(dx * dx + dy * dy + dz * dz + dw * dw) * (1.f / 256.f);
    float rs = rsqrtf(var + LEPS);
    float4 gv = *(const float4*)(g + (lane << 2));
    float4 bv = *(const float4*)(be + (lane << 2));
    float4 y;
    y.x = dx * rs * gv.x + bv.x;
    y.y = dy * rs * gv.y + bv.y;
    y.z = dz * rs * gv.z + bv.z;
    y.w = dw * rs * gv.w + bv.w;
    *(float4*)(outp + row * C1 + (lane << 2)) = y;
}

extern "C" void kernel_launch(void* const* d_in, const int* in_sizes, int n_in,
                              void* d_out, int out_size, void* d_ws, size_t ws_size,
                              hipStream_t stream) {
    const float* x    = (const float*)d_in[0];
    const float* emb  = (const float*)d_in[1];
    const float* w1l  = (const float*)d_in[2];
    const float* b1l  = (const float*)d_in[3];
    const float* w1r  = (const float*)d_in[4];
    const float* b1r  = (const float*)d_in[5];
    const float* att1 = (const float*)d_in[6];
    const float* bia1 = (const float*)d_in[7];
    const float* g1   = (const float*)d_in[8];
    const float* be1  = (const float*)d_in[9];
    const float* w2l  = (const float*)d_in[10];
    const float* b2l  = (const float*)d_in[11];
    const float* w2r  = (const float*)d_in[12];
    const float* b2r  = (const float*)d_in[13];
    const float* att2 = (const float*)d_in[14];
    const float* bia2 = (const float*)d_in[15];
    const float* g2   = (const float*)d_in[16];
    const float* be2  = (const float*)d_in[17];

    char* w = (char*)d_ws;
    float* xl           = (float*)w;         w += (size_t)BB * NN * C1 * 4;  // 1 MB
    float* xr           = (float*)w;         w += (size_t)BB * NN * C1 * 4;  // 1 MB
    float* ho           = (float*)w;         w += (size_t)BB * NN * C1 * 4;  // 1 MB
    unsigned char* mask = (unsigned char*)w; w += (size_t)NN * NN;           // 256 KB

    mask_k<<<dim3(NN / TI, 4), 256, 0, stream>>>(emb, mask);
    proj1_k<<<BB * NN / 4, 256, 0, stream>>>(x, w1l, b1l, w1r, b1r, xl, xr);
    attn_k<<<dim3(NN / TI, HH, BB), 256, 0, stream>>>(xl, xr, att1, bia1, mask, ho);
    projln_k<<<BB * NN / 4, 256, 0, stream>>>(ho, g1, be1, w2l, b2l, w2r, b2r, xl, xr);
    attn_k<<<dim3(NN / TI, HH, BB), 256, 0, stream>>>(xl, xr, att2, bia2, mask, ho);
    ln2_k<<<BB * NN / 4, 256, 0, stream>>>(ho, g2, be2, (float*)d_out);
}

// Round 7
// 244.818 us; speedup vs baseline: 1.2701x; 1.1514x over previous
//
#include <hip/hip_runtime.h>
#include <hip/hip_bf16.h>
#include <cfloat>

// GATv2 x2 + LayerNorm, B=2 N=512 DIN=32 DH=DOUT=64 H=4. fp32 in/out.
// R7: col-split projections (4 blk/CU), online-softmax single-pass attention
// with bit-packed mask + register-resident xr fragments.

#define BB   2
#define NN   512
#define DIN  32
#define DH   64
#define HH   4
#define C1   256
#define C2   256
#define TI   16
#define XP   68    // xbuf pitch (floats): 16B-aligned b128, uniform bank spread
#define LEPS 1e-5f

__device__ __forceinline__ float bf_sum(float v) {
#pragma unroll
    for (int o = 32; o > 0; o >>= 1) v += __shfl_xor(v, o, 64);
    return v;
}
__device__ __forceinline__ float bf_max(float v) {
#pragma unroll
    for (int o = 32; o > 0; o >>= 1) v = fmaxf(v, __shfl_xor(v, o, 64));
    return v;
}

// --- packed mask: bit j of mask64[i*8 + j/64] = (dot(emb_i,emb_j)!=0 || i==j)
// Raw dot has the same zero-set as the normalized cosine dot.
__global__ __launch_bounds__(256) void mask_k(const float* __restrict__ emb,
                                              unsigned long long* __restrict__ mask64) {
    __shared__ __align__(16) float s_ei[TI][DH];
    __shared__ float ebuf[64][DH + 1];
    int it = blockIdx.x, jq = blockIdx.y;
    int t = threadIdx.x, lane = t & 63, iq = t >> 6;
    {
        int row = t >> 4, d4 = (t & 15) << 2;
        *(float4*)&s_ei[row][d4] = *(const float4*)(emb + (it * TI + row) * DH + d4);
    }
    for (int jt = 0; jt < 2; jt++) {
        int j0 = jq * 128 + jt * 64;
        __syncthreads();
#pragma unroll
        for (int k = 0; k < 4; k++) {
            int idx = k * 256 + t, jl = idx >> 4, d4 = (idx & 15) << 2;
            float4 v = *(const float4*)(emb + (j0 + jl) * DH + d4);
            ebuf[jl][d4] = v.x; ebuf[jl][d4 + 1] = v.y;
            ebuf[jl][d4 + 2] = v.z; ebuf[jl][d4 + 3] = v.w;
        }
        __syncthreads();
        float acc[4] = {0.f, 0.f, 0.f, 0.f};
        for (int dc = 0; dc < 16; dc++) {
            int d = dc * 4;
            float e0 = ebuf[lane][d], e1 = ebuf[lane][d + 1];
            float e2 = ebuf[lane][d + 2], e3 = ebuf[lane][d + 3];
#pragma unroll
            for (int r = 0; r < 4; r++) {
                float4 iv = *(const float4*)&s_ei[iq * 4 + r][d];
                acc[r] += iv.x * e0 + iv.y * e1 + iv.z * e2 + iv.w * e3;
            }
        }
        int jg = j0 + lane;
#pragma unroll
        for (int r = 0; r < 4; r++) {
            int ig = it * TI + iq * 4 + r;
            unsigned long long bal = __ballot(acc[r] != 0.f || ig == jg);
            if (lane == 0) mask64[ig * 8 + (j0 >> 6)] = bal;
        }
    }
}

// --- proj1: grid (BB*NN/4, 4 colquads). thread: 2 rows x 1 col, K=32 ---
__global__ __launch_bounds__(256) void proj1_k(const float* __restrict__ x,
        const float* __restrict__ wl, const float* __restrict__ bl,
        const float* __restrict__ wr, const float* __restrict__ br,
        float* __restrict__ xl, float* __restrict__ xr) {
    __shared__ float s_x[4][DIN];
    int t = threadIdx.x, row0 = blockIdx.x * 4, cq = blockIdx.y;
    if (t < 128) s_x[t >> 5][t & 31] = x[(row0 + (t >> 5)) * DIN + (t & 31)];
    __syncthreads();
    int cl = t & 127, half = t >> 7;
    int gc = cq * 128 + cl;
    const float* wbase; float bias; float* obase; int oc;
    if (gc < C1) { wbase = wl + gc; bias = bl[gc]; obase = xl; oc = gc; }
    else         { wbase = wr + gc - C1; bias = br[gc - C1]; obase = xr; oc = gc - C1; }
    int ra = half * 2, rb = ra + 1;
    float a0 = bias, a1 = bias;
#pragma unroll
    for (int k = 0; k < DIN; k++) {
        float wv = wbase[(size_t)k * C1];
        a0 += s_x[ra][k] * wv;
        a1 += s_x[rb][k] * wv;
    }
    obase[(size_t)(row0 + ra) * C1 + oc] = a0;
    obase[(size_t)(row0 + rb) * C1 + oc] = a1;
}

// --- fused LN(g1,be1)+ReLU + proj2. grid (BB*NN/4, 4 colquads). ---
__global__ __launch_bounds__(256) void projln_k(const float* __restrict__ ho,
        const float* __restrict__ g, const float* __restrict__ be,
        const float* __restrict__ wl, const float* __restrict__ bl,
        const float* __restrict__ wr, const float* __restrict__ br,
        float* __restrict__ xl, float* __restrict__ xr) {
    __shared__ __align__(16) float s_h[4][C1];
    int t = threadIdx.x, lane = t & 63, w = t >> 6;
    int row0 = blockIdx.x * 4, cq = blockIdx.y;
    {   // wave w LN+ReLU of row row0+w
        const float* src = ho + (size_t)(row0 + w) * C1;
        float4 v = *(const float4*)(src + (lane << 2));
        float mu = bf_sum(v.x + v.y + v.z + v.w) * (1.f / 256.f);
        float dx = v.x - mu, dy = v.y - mu, dz = v.z - mu, dw = v.w - mu;
        float var = bf_sum(dx * dx + dy * dy + dz * dz + dw * dw) * (1.f / 256.f);
        float rs = rsqrtf(var + LEPS);
        float4 gv = *(const float4*)(g + (lane << 2));
        float4 bv = *(const float4*)(be + (lane << 2));
        float4 y;
        y.x = fmaxf(dx * rs * gv.x + bv.x, 0.f);
        y.y = fmaxf(dy * rs * gv.y + bv.y, 0.f);
        y.z = fmaxf(dz * rs * gv.z + bv.z, 0.f);
        y.w = fmaxf(dw * rs * gv.w + bv.w, 0.f);
        *(float4*)&s_h[w][lane << 2] = y;
    }
    __syncthreads();
    int cl = t & 127, half = t >> 7;
    int gc = cq * 128 + cl;
    const float* wbase; float bias; float* obase; int oc;
    if (gc < C2) { wbase = wl + gc; bias = bl[gc]; obase = xl; oc = gc; }
    else         { wbase = wr + gc - C2; bias = br[gc - C2]; obase = xr; oc = gc - C2; }
    int ra = half * 2, rb = ra + 1;
    float a0 = bias, a1 = bias;
#pragma unroll 8
    for (int k = 0; k < C1; k++) {
        float wv = wbase[(size_t)k * C2];
        a0 += s_h[ra][k] * wv;
        a1 += s_h[rb][k] * wv;
    }
    obase[(size_t)(row0 + ra) * C2 + oc] = a0;
    obase[(size_t)(row0 + rb) * C2 + oc] = a1;
}

// --- GATv2 attention, online softmax, single xl pass. ---
// Block = (i-tile 16, h, b), 256 thr. Wave iq owns rows iq*4..+3.
// xr fragments hoisted to registers (rxr[4][16] float4, ~330 VGPR @ 1 wave/SIMD).
__global__ __launch_bounds__(256, 1) void attn_k(const float* __restrict__ xl,
        const float* __restrict__ xr, const float* __restrict__ att,
        const float* __restrict__ bias, const unsigned long long* __restrict__ mask64,
        float* __restrict__ out) {
    __shared__ __align__(16) float s_xr[TI][DH];
    __shared__ __align__(16) float s_att[DH];
    __shared__ __align__(16) float xbuf[64][XP];
    __shared__ __align__(16) float s_p[TI][64];
    __shared__ unsigned long long s_m64[TI * 8];

    int it = blockIdx.x, h = blockIdx.y, b = blockIdx.z;
    int t = threadIdx.x, lane = t & 63, iq = t >> 6;
    int i0 = it * TI;

    {   // stage xr i-tile
        int row = t >> 4, d4 = (t & 15) << 2;
        *(float4*)&s_xr[row][d4] =
            *(const float4*)(xr + (size_t)(b * NN + i0 + row) * C1 + h * DH + d4);
    }
    if (t < DH) s_att[t] = att[h * DH + t];
    if (t < TI * 8) s_m64[t] = mask64[i0 * 8 + t];
    __syncthreads();

    // hoist wave's 4 xr rows into registers (64 float4)
    float4 rxr[4][16];
#pragma unroll
    for (int r = 0; r < 4; r++)
#pragma unroll
        for (int dc = 0; dc < 16; dc++)
            rxr[r][dc] = *(const float4*)&s_xr[iq * 4 + r][dc << 2];

    int pidx[4][2];
#pragma unroll
    for (int k = 0; k < 4; k++) {
        int idx = k * 256 + t;
        pidx[k][0] = idx >> 4;            // j-local row
        pidx[k][1] = (idx & 15) << 2;     // d4
    }
    const float* xlbase = xl + (size_t)b * NN * C1 + h * DH;

    float m_r[4], l_r[4], agg[4];
#pragma unroll
    for (int r = 0; r < 4; r++) { m_r[r] = -FLT_MAX; l_r[r] = 0.f; agg[r] = 0.f; }

    float4 xa[4];
#pragma unroll
    for (int k = 0; k < 4; k++)
        xa[k] = *(const float4*)(xlbase + (size_t)pidx[k][0] * C1 + pidx[k][1]);

    for (int jt = 0; jt < 8; jt++) {
        __syncthreads();   // xbuf free (prev tile fully consumed)
#pragma unroll
        for (int k = 0; k < 4; k++)
            *(float4*)&xbuf[pidx[k][0]][pidx[k][1]] = xa[k];
        __syncthreads();   // xbuf ready
        if (jt < 7) {
#pragma unroll
            for (int k = 0; k < 4; k++)
                xa[k] = *(const float4*)(xlbase + (size_t)((jt + 1) * 64 + pidx[k][0]) * C1 + pidx[k][1]);
        }

        // ---- scores for j = jt*64 + lane, rows iq*4..+3 ----
        float acc1[4] = {0.f, 0.f, 0.f, 0.f}, acc2[4] = {0.f, 0.f, 0.f, 0.f};
#pragma unroll
        for (int dc = 0; dc < 16; dc++) {
            float4 xv = *(const float4*)&xbuf[lane][dc << 2];
            float4 av = *(const float4*)&s_att[dc << 2];
#pragma unroll
            for (int r = 0; r < 4; r++) {
                float z0 = xv.x + rxr[r][dc].x, z1 = xv.y + rxr[r][dc].y;
                float z2 = xv.z + rxr[r][dc].z, z3 = xv.w + rxr[r][dc].w;
                acc1[r] += av.x * z0 + av.y * z1 + av.z * z2 + av.w * z3;
                acc2[r] += av.x * fabsf(z0) + av.y * fabsf(z1)
                         + av.z * fabsf(z2) + av.w * fabsf(z3);
            }
        }
        // ---- online softmax update (wave-private rows) ----
#pragma unroll
        for (int r = 0; r < 4; r++) {
            int il = iq * 4 + r;
            unsigned long long mw = s_m64[il * 8 + jt];
            bool live = (mw >> lane) & 1ull;
            // leaky_relu(z) = 0.6z + 0.4|z| for slope 0.2 (linear in the att-dot)
            float e = 0.6f * acc1[r] + 0.4f * acc2[r];
            float ev = live ? e : -FLT_MAX;
            float mn = fmaxf(m_r[r], bf_max(ev));
            float alpha = (m_r[r] == -FLT_MAX) ? 0.f : __expf(m_r[r] - mn);
            float p = live ? __expf(e - mn) : 0.f;
            l_r[r] = l_r[r] * alpha + bf_sum(p);
            agg[r] *= alpha;
            m_r[r] = mn;
            s_p[il][lane] = p;
        }
        __threadfence_block();   // drain LDS writes (same-wave cross-lane reads next)

        // ---- aggregate this tile: agg[r] (d = lane) += sum_j p_j * xl[j][d] ----
#pragma unroll
        for (int jc = 0; jc < 16; jc++) {
            int j = jc << 2;
            float x0 = xbuf[j][lane], x1 = xbuf[j + 1][lane];
            float x2 = xbuf[j + 2][lane], x3 = xbuf[j + 3][lane];
#pragma unroll
            for (int r = 0; r < 4; r++) {
                float4 p = *(const float4*)&s_p[iq * 4 + r][j];
                agg[r] += p.x * x0 + p.y * x1 + p.z * x2 + p.w * x3;
            }
        }
    }

    float bv = bias[h * DH + lane];
#pragma unroll
    for (int r = 0; r < 4; r++) {
        int il = iq * 4 + r;
        out[(size_t)(b * NN + i0 + il) * C1 + h * DH + lane] = agg[r] / l_r[r] + bv;
    }
}

// --- final LayerNorm, wave-per-row ---
__global__ __launch_bounds__(256) void ln2_k(const float* __restrict__ in,
        const float* __restrict__ g, const float* __restrict__ be,
        float* __restrict__ outp) {
    int t = threadIdx.x, lane = t & 63, w = t >> 6;
    size_t row = blockIdx.x * 4 + w;
    float4 v = *(const float4*)(in + row * C1 + (lane << 2));
    float mu = bf_sum(v.x + v.y + v.z + v.w) * (1.f / 256.f);
    float dx = v.x - mu, dy = v.y - mu, dz = v.z - mu, dw = v.w - mu;
    float var = bf_sum(dx * dx + dy * dy + dz * dz + dw * dw) * (1.f / 256.f);
    float rs = rsqrtf(var + LEPS);
    float4 gv = *(const float4*)(g + (lane << 2));
    float4 bv = *(const float4*)(be + (lane << 2));
    float4 y;
    y.x = dx * rs * gv.x + bv.x;
    y.y = dy * rs * gv.y + bv.y;
    y.z = dz * rs * gv.z + bv.z;
    y.w = dw * rs * gv.w + bv.w;
    *(float4*)(outp + row * C1 + (lane << 2)) = y;
}

extern "C" void kernel_launch(void* const* d_in, const int* in_sizes, int n_in,
                              void* d_out, int out_size, void* d_ws, size_t ws_size,
                              hipStream_t stream) {
    const float* x    = (const float*)d_in[0];
    const float* emb  = (const float*)d_in[1];
    const float* w1l  = (const float*)d_in[2];
    const float* b1l  = (const float*)d_in[3];
    const float* w1r  = (const float*)d_in[4];
    const float* b1r  = (const float*)d_in[5];
    const float* att1 = (const float*)d_in[6];
    const float* bia1 = (const float*)d_in[7];
    const float* g1   = (const float*)d_in[8];
    const float* be1  = (const float*)d_in[9];
    const float* w2l  = (const float*)d_in[10];
    const float* b2l  = (const float*)d_in[11];
    const float* w2r  = (const float*)d_in[12];
    const float* b2r  = (const float*)d_in[13];
    const float* att2 = (const float*)d_in[14];
    const float* bia2 = (const float*)d_in[15];
    const float* g2   = (const float*)d_in[16];
    const float* be2  = (const float*)d_in[17];

    char* w = (char*)d_ws;
    float* xl                  = (float*)w;              w += (size_t)BB * NN * C1 * 4;
    float* xr                  = (float*)w;              w += (size_t)BB * NN * C1 * 4;
    float* ho                  = (float*)w;              w += (size_t)BB * NN * C1 * 4;
    unsigned long long* mask64 = (unsigned long long*)w; w += (size_t)NN * 8 * 8;

    mask_k<<<dim3(NN / TI, 4), 256, 0, stream>>>(emb, mask64);
    proj1_k<<<dim3(BB * NN / 4, 4), 256, 0, stream>>>(x, w1l, b1l, w1r, b1r, xl, xr);
    attn_k<<<dim3(NN / TI, HH, BB), 256, 0, stream>>>(xl, xr, att1, bia1, mask64, ho);
    projln_k<<<dim3(BB * NN / 4, 4), 256, 0, stream>>>(ho, g1, be1, w2l, b2l, w2r, b2r, xl, xr);
    attn_k<<<dim3(NN / TI, HH, BB), 256, 0, stream>>>(xl, xr, att2, bia2, mask64, ho);
    ln2_k<<<BB * NN / 4, 256, 0, stream>>>(ho, g2, be2, (float*)d_out);
}